// Round 3
// baseline (370.699 us; speedup 1.0000x reference)
//
#include <hip/hip_runtime.h>
#include <hip/hip_bf16.h>
#include <cstdint>
#include <cstddef>

#define HH 1024
#define BB 8
#define TT 2048
#define MM (BB*TT)   // 16384
#define CC 128       // wkv chunks
#define LL (TT/CC)   // 16 steps per chunk

typedef __attribute__((ext_vector_type(8))) short bf16x8;
typedef __attribute__((ext_vector_type(8))) unsigned short u16x8;
typedef __attribute__((ext_vector_type(4))) float f32x4;

__device__ __forceinline__ unsigned short f2bf(float f) {
  union { float f; unsigned u; } v; v.f = f;
  return (unsigned short)((v.u + 0x7fffu + ((v.u >> 16) & 1u)) >> 16);  // RNE
}
__device__ __forceinline__ float bf2f(unsigned short s) {
  union { float f; unsigned u; } v; v.u = ((unsigned)s) << 16;
  return v.f;
}

__device__ __forceinline__ void load_lds16(const void* g, void* l) {
  __builtin_amdgcn_global_load_lds((const __attribute__((address_space(1))) void*)g,
                                   (__attribute__((address_space(3))) void*)l,
                                   16, 0, 0);
}

// ---------------- weight fp32 -> bf16 ----------------
__global__ __launch_bounds__(256) void conv_w(const float* __restrict__ Wk,
    const float* __restrict__ Wv, const float* __restrict__ Wr,
    const float* __restrict__ Wo, unsigned short* __restrict__ dst) {
  const int i = (blockIdx.x * 256 + threadIdx.x) * 4;
  const float* src = blockIdx.y == 0 ? Wk : blockIdx.y == 1 ? Wv : blockIdx.y == 2 ? Wr : Wo;
  const float4 v = *(const float4*)(src + i);
  ushort4 o; o.x = f2bf(v.x); o.y = f2bf(v.y); o.z = f2bf(v.z); o.w = f2bf(v.w);
  *(ushort4*)(dst + (size_t)blockIdx.y * HH * HH + i) = o;
}

// ---------------- time-shift + mix -> bf16 kin/vin/rin ----------------
__global__ __launch_bounds__(256) void mix_kernel(const float* __restrict__ x,
    const float* __restrict__ tmk, const float* __restrict__ tmv, const float* __restrict__ tmr,
    unsigned short* __restrict__ kin, unsigned short* __restrict__ vin,
    unsigned short* __restrict__ rin) {
  const int gid = blockIdx.x * 256 + threadIdx.x;
  const size_t e0 = (size_t)gid * 4;
  const int h = (int)(e0 & (HH - 1));
  const int t = (int)((e0 >> 10) & (TT - 1));
  const float4 xv = *(const float4*)(x + e0);
  float4 sv = make_float4(0.f, 0.f, 0.f, 0.f);
  if (t != 0) sv = *(const float4*)(x + e0 - HH);
  const float4 k4 = *(const float4*)(tmk + h);
  const float4 v4 = *(const float4*)(tmv + h);
  const float4 r4 = *(const float4*)(tmr + h);
  ushort4 ko, vo, ro;
  ko.x = f2bf(sv.x + k4.x * (xv.x - sv.x)); ko.y = f2bf(sv.y + k4.y * (xv.y - sv.y));
  ko.z = f2bf(sv.z + k4.z * (xv.z - sv.z)); ko.w = f2bf(sv.w + k4.w * (xv.w - sv.w));
  vo.x = f2bf(sv.x + v4.x * (xv.x - sv.x)); vo.y = f2bf(sv.y + v4.y * (xv.y - sv.y));
  vo.z = f2bf(sv.z + v4.z * (xv.z - sv.z)); vo.w = f2bf(sv.w + v4.w * (xv.w - sv.w));
  ro.x = f2bf(sv.x + r4.x * (xv.x - sv.x)); ro.y = f2bf(sv.y + r4.y * (xv.y - sv.y));
  ro.z = f2bf(sv.z + r4.z * (xv.z - sv.z)); ro.w = f2bf(sv.w + r4.w * (xv.w - sv.w));
  *(ushort4*)(kin + e0) = ko;
  *(ushort4*)(vin + e0) = vo;
  *(ushort4*)(rin + e0) = ro;
}

// ================= 256x256 8-phase GEMM core (r3: 2-bit bank swizzle) ==========
// BM=BN=256, BK=64, 8 waves (2M x 4N), LDS 128 KiB (2 dbuf x A/B x 256x64 bf16).
// Row stride = 128 B = 32 dwords, so bank = f(column only). r2's 1-bit swizzle left
// reads in banks 0-15 (4-way, measured 9.4M conflicts = +4 cy/read). r3 swizzle:
//   f(row) = ((row>>2)&1)<<4 | ((row>>3)&1)<<5   (element-col XOR)
// Read: row bits 2,3 = lane bits 2,3; 64 lanes' 4-bank groups cover all 32 banks,
// 8 dwords/bank = minimal (2-way aliasing is free, m136).
// Write (linear global_load_lds dest + pre-swizzled source, rule #21): row =
// base + (lane>>3), base bit3 = w&1 for stA/stB -> scol ^= ((lane>>5)&1)<<4 ^ (w&1)<<5.
// vmcnt(6) only at phases 4/8 (counted vmcnt); final vmcnt(0) drain before exit.

#define BAR()   do { asm volatile("" ::: "memory"); __builtin_amdgcn_s_barrier(); \
                     asm volatile("" ::: "memory"); } while (0)
#define LGKM0() asm volatile("s_waitcnt lgkmcnt(0)" ::: "memory")
#define VM6()   asm volatile("s_waitcnt vmcnt(6)" ::: "memory")
#define VM0()   asm volatile("s_waitcnt vmcnt(0)" ::: "memory")

__device__ __forceinline__ void stA(const unsigned short* __restrict__ Ag, int m0, int kt,
                                    unsigned short* buf, int h, int w, int rl, int scol) {
#pragma unroll
  for (int l = 0; l < 2; ++l) {
    const int row = l * 128 + h * 64 + w * 8;          // wave-uniform dest row base
    load_lds16(Ag + (size_t)(m0 + row + rl) * HH + kt + scol, buf + row * 64);
  }
}
__device__ __forceinline__ void stB(const unsigned short* __restrict__ Bg, int n0, int kt,
                                    unsigned short* buf, int h, int w, int rl, int scol) {
#pragma unroll
  for (int l = 0; l < 2; ++l) {
    const int row = (2 * (l * 2 + (w >> 2)) + h) * 32 + (w & 3) * 8;
    load_lds16(Bg + (size_t)(n0 + row + rl) * HH + kt + scol, buf + row * 64);
  }
}

template<int MH>
__device__ __forceinline__ void rdA(const unsigned short* buf, bf16x8 (&af)[4][2],
                                    int wm, int l15, int kq, int swz) {
#pragma unroll
  for (int fm = 0; fm < 4; ++fm)
#pragma unroll
    for (int kk = 0; kk < 2; ++kk)
      af[fm][kk] = *(const bf16x8*)(buf + (wm * 128 + MH * 64 + fm * 16 + l15) * 64
                                        + ((kk * 32 + kq * 8) ^ swz));
}
template<int NH>
__device__ __forceinline__ void rdB(const unsigned short* buf, bf16x8 (&bfr)[2][2][2],
                                    int wn, int l15, int kq, int swz) {
#pragma unroll
  for (int fn = 0; fn < 2; ++fn)
#pragma unroll
    for (int kk = 0; kk < 2; ++kk)
      bfr[NH][fn][kk] = *(const bf16x8*)(buf + (wn * 64 + NH * 32 + fn * 16 + l15) * 64
                                             + ((kk * 32 + kq * 8) ^ swz));
}
template<int MH, int NH>
__device__ __forceinline__ void mfmaQ(f32x4 (&acc)[8][4], const bf16x8 (&af)[4][2],
                                      const bf16x8 (&bfr)[2][2][2]) {
  __builtin_amdgcn_s_setprio(1);
#pragma unroll
  for (int kk = 0; kk < 2; ++kk)
#pragma unroll
    for (int fm = 0; fm < 4; ++fm)
#pragma unroll
      for (int fn = 0; fn < 2; ++fn)
        acc[MH * 4 + fm][NH * 2 + fn] = __builtin_amdgcn_mfma_f32_16x16x32_bf16(
            af[fm][kk], bfr[NH][fn][kk], acc[MH * 4 + fm][NH * 2 + fn], 0, 0, 0);
  __builtin_amdgcn_s_setprio(0);
}

__device__ __forceinline__ void gemm256(const unsigned short* __restrict__ Ag,
                                        const unsigned short* __restrict__ Bg,
                                        const int m0, const int n0,
                                        unsigned short* As, unsigned short* Bs,
                                        f32x4 (&acc)[8][4]) {
  const int tid = threadIdx.x;
  const int lane = tid & 63;
  const int w = tid >> 6;
  const int wm = w >> 2, wn = w & 3;
  const int l15 = lane & 15, kq = lane >> 4;
  // read-side XOR: row bits 2,3 (= lane bits 2,3) -> element-col bits 4,5
  const int swz = (((lane >> 2) & 1) << 4) | (((lane >> 3) & 1) << 5);
  const int rl = lane >> 3;                                     // stage source row-in-8
  // write-side pre-swizzle of global source col: row bit2 = lane bit5, row bit3 = w&1
  const int scol = (((lane & 7) * 8) ^ (((lane >> 5) & 1) << 4)) ^ ((w & 1) << 5);
  unsigned short* const A0 = As;
  unsigned short* const A1 = As + 256 * 64;
  unsigned short* const B0 = Bs;
  unsigned short* const B1 = Bs + 256 * 64;
  bf16x8 af[4][2], bfr[2][2][2];

  // prologue: tile0 -> buf0 (8 loads), tile1 A0,B0,B1 -> buf1 (6 loads); drain buf0.
  stA(Ag, m0, 0, A0, 0, w, rl, scol);
  stB(Bg, n0, 0, B0, 0, w, rl, scol);
  stB(Bg, n0, 0, B0, 1, w, rl, scol);
  stA(Ag, m0, 0, A0, 1, w, rl, scol);
  stA(Ag, m0, 64, A1, 0, w, rl, scol);
  stB(Bg, n0, 64, B1, 0, w, rl, scol);
  stB(Bg, n0, 64, B1, 1, w, rl, scol);
  VM6(); BAR();

#pragma unroll 1
  for (int i = 0; i < 8; ++i) {
    const int tb1 = ((2 * i + 1) * 64) & (HH - 1);  // buf1 current tile (A1 staged ph1)
    const int tn0 = ((2 * i + 2) * 64) & (HH - 1);  // buf0 next tile (wraps harmlessly @end)
    const int tn1 = ((2 * i + 3) * 64) & (HH - 1);  // buf1 next tile
    // ph1: compute (mh0,nh0) of buf0; stage buf1.A-h1 (WAR: read ph7 prev iter)
    rdA<0>(A0, af, wm, l15, kq, swz); rdB<0>(B0, bfr, wn, l15, kq, swz);
    stA(Ag, m0, tb1, A1, 1, w, rl, scol);
    BAR(); LGKM0(); mfmaQ<0, 0>(acc, af, bfr); BAR();
    // ph2: (mh0,nh1); stage buf0.A-h0 (read ph1)
    rdB<1>(B0, bfr, wn, l15, kq, swz);
    stA(Ag, m0, tn0, A0, 0, w, rl, scol);
    BAR(); LGKM0(); mfmaQ<0, 1>(acc, af, bfr); BAR();
    // ph3: (mh1,nh1); stage buf0.B-h0 (read ph1)
    rdA<1>(A0, af, wm, l15, kq, swz);
    stB(Bg, n0, tn0, B0, 0, w, rl, scol);
    BAR(); LGKM0(); mfmaQ<1, 1>(acc, af, bfr); BAR();
    // ph4: (mh1,nh0); stage buf0.B-h1 (read ph2); counted vmcnt (drains buf1 cur tile)
    stB(Bg, n0, tn0, B0, 1, w, rl, scol);
    VM6(); BAR(); LGKM0(); mfmaQ<1, 0>(acc, af, bfr); BAR();
    // ph5: (mh0,nh0) of buf1; stage buf0.A-h1 (read ph3)
    rdA<0>(A1, af, wm, l15, kq, swz); rdB<0>(B1, bfr, wn, l15, kq, swz);
    stA(Ag, m0, tn0, A0, 1, w, rl, scol);
    BAR(); LGKM0(); mfmaQ<0, 0>(acc, af, bfr); BAR();
    // ph6: (mh0,nh1); stage buf1.A-h0 (read ph5)
    rdB<1>(B1, bfr, wn, l15, kq, swz);
    stA(Ag, m0, tn1, A1, 0, w, rl, scol);
    BAR(); LGKM0(); mfmaQ<0, 1>(acc, af, bfr); BAR();
    // ph7: (mh1,nh1); stage buf1.B-h0 (read ph5)
    rdA<1>(A1, af, wm, l15, kq, swz);
    stB(Bg, n0, tn1, B1, 0, w, rl, scol);
    BAR(); LGKM0(); mfmaQ<1, 1>(acc, af, bfr); BAR();
    // ph8: (mh1,nh0); stage buf1.B-h1 (read ph6); counted vmcnt (drains buf0 next tile)
    stB(Bg, n0, tn1, B1, 1, w, rl, scol);
    VM6(); BAR(); LGKM0(); mfmaQ<1, 0>(acc, af, bfr); BAR();
  }
  // no DMA may outlive this workgroup's LDS allocation (1 wg/CU -> successor reuses it)
  VM0();
}

// XCD-aware swizzle for 256 wgs (0 mod 8 -> bijective): 32 contiguous tiles per XCD.
__device__ __forceinline__ void swizzle_mn256(int x, int& m0, int& n0) {
  const int wg = (x & 7) * 32 + (x >> 3);
  m0 = (wg >> 2) * 256;          // 64 m-tiles
  n0 = (wg & 3) * 256;           // 4 n-tiles
}

// z=0: k -> bf16, z=1: v -> bf16, z=2: r -> sigmoid -> bf16
__global__ __launch_bounds__(512, 2) void gemm_kvr(const unsigned short* __restrict__ kin,
    const unsigned short* __restrict__ vin, const unsigned short* __restrict__ rin,
    const unsigned short* __restrict__ Wbf,
    unsigned short* __restrict__ kb, unsigned short* __restrict__ vb,
    unsigned short* __restrict__ rb) {
  __shared__ unsigned short As[2 * 256 * 64];
  __shared__ unsigned short Bs[2 * 256 * 64];
  const int z = blockIdx.y;
  const unsigned short* Ag = z == 0 ? kin : (z == 1 ? vin : rin);
  const unsigned short* Bg = Wbf + (size_t)z * HH * HH;
  unsigned short* Cg = z == 0 ? kb : (z == 1 ? vb : rb);
  int m0, n0; swizzle_mn256(blockIdx.x, m0, n0);
  f32x4 acc[8][4] = {};
  gemm256(Ag, Bg, m0, n0, As, Bs, acc);
  const int lane = threadIdx.x & 63, w = threadIdx.x >> 6;
  const int wm = w >> 2, wn = w & 3, l15 = lane & 15, lq = lane >> 4;
  const bool sig = (z == 2);
#pragma unroll
  for (int fm = 0; fm < 8; ++fm)
#pragma unroll
    for (int fn = 0; fn < 4; ++fn) {
      const int col = n0 + wn * 64 + fn * 16 + l15;
      const int r0 = m0 + wm * 128 + fm * 16 + lq * 4;
#pragma unroll
      for (int j = 0; j < 4; ++j) {
        float vv = acc[fm][fn][j];
        if (sig) vv = 1.0f / (1.0f + __expf(-vv));
        Cg[(size_t)(r0 + j) * HH + col] = f2bf(vv);
      }
    }
}

// out = rwkv @ Wo^T + bo  (fp32 out)
__global__ __launch_bounds__(512, 2) void gemm_o(const unsigned short* __restrict__ Ag,
    const unsigned short* __restrict__ Bg, const float* __restrict__ bias,
    float* __restrict__ C) {
  __shared__ unsigned short As[2 * 256 * 64];
  __shared__ unsigned short Bs[2 * 256 * 64];
  int m0, n0; swizzle_mn256(blockIdx.x, m0, n0);
  f32x4 acc[8][4] = {};
  gemm256(Ag, Bg, m0, n0, As, Bs, acc);
  const int lane = threadIdx.x & 63, w = threadIdx.x >> 6;
  const int wm = w >> 2, wn = w & 3, l15 = lane & 15, lq = lane >> 4;
#pragma unroll
  for (int fm = 0; fm < 8; ++fm)
#pragma unroll
    for (int fn = 0; fn < 4; ++fn) {
      const int col = n0 + wn * 64 + fn * 16 + l15;
      const float bv = bias[col];
      const int r0 = m0 + wm * 128 + fm * 16 + lq * 4;
#pragma unroll
      for (int j = 0; j < 4; ++j)
        C[(size_t)(r0 + j) * HH + col] = acc[fm][fn][j] + bv;
    }
}

// ---------------- WKV: chunk-parallel scan over T (r3: 8-wide vectorized) ----------------
__global__ __launch_bounds__(256) void wkv_part(const unsigned short* __restrict__ k,
    const unsigned short* __restrict__ v, const float* __restrict__ tdec,
    float* __restrict__ pnum, float* __restrict__ pden) {
  const int gid = blockIdx.x * 256 + threadIdx.x;   // 0 .. CC*BB*HH/8-1
  const int h0 = (gid & 127) * 8;
  const int b = (gid >> 7) & (BB - 1);
  const int c = gid >> 10;
  float td[8], num[8], den[8];
#pragma unroll
  for (int j = 0; j < 8; ++j) {
    td[j] = __expf(-__expf(tdec[h0 + j]));
    num[j] = 0.f; den[j] = 0.f;
  }
  size_t idx = (size_t)b * TT * HH + (size_t)(c * LL) * HH + h0;
#pragma unroll 4
  for (int i = 0; i < LL; ++i, idx += HH) {
    const u16x8 k8 = *(const u16x8*)(k + idx);
    const u16x8 v8 = *(const u16x8*)(v + idx);
#pragma unroll
    for (int j = 0; j < 8; ++j) {
      const float ek = __expf(bf2f(k8[j]));
      num[j] = td[j] * num[j] + ek * bf2f(v8[j]);
      den[j] = td[j] * den[j] + ek;
    }
  }
  const size_t o = (size_t)c * (BB * HH) + b * HH + h0;
#pragma unroll
  for (int j = 0; j < 8; ++j) { pnum[o + j] = num[j]; pden[o + j] = den[j]; }
}

__global__ __launch_bounds__(256) void wkv_scan(const float* __restrict__ tdec,
    float* __restrict__ pnum, float* __restrict__ pden) {
  const int bh = blockIdx.x * 256 + threadIdx.x;     // 0..8191
  const int h = bh & (HH - 1);
  const float ed = __expf(tdec[h]);
  const float tdL = __expf(-ed * (float)LL);         // td^LL exactly
  float num = 0.f, den = 0.f;
#pragma unroll 8
  for (int c = 0; c < CC; ++c) {
    const size_t o = (size_t)c * (BB * HH) + bh;
    const float tn = pnum[o], td_ = pden[o];
    pnum[o] = num; pden[o] = den;
    num = tdL * num + tn;
    den = tdL * den + td_;
  }
}

__global__ __launch_bounds__(256) void wkv_final(const unsigned short* __restrict__ k,
    const unsigned short* __restrict__ v, const unsigned short* __restrict__ r,
    const float* __restrict__ tdec, const float* __restrict__ tfst,
    const float* __restrict__ pnum, const float* __restrict__ pden,
    unsigned short* __restrict__ rwkv) {
  const int gid = blockIdx.x * 256 + threadIdx.x;   // 0 .. CC*BB*HH/8-1
  const int h0 = (gid & 127) * 8;
  const int b = (gid >> 7) & (BB - 1);
  const int c = gid >> 10;
  float td[8], etf[8], num[8], den[8];
  const size_t o = (size_t)c * (BB * HH) + b * HH + h0;
#pragma unroll
  for (int j = 0; j < 8; ++j) {
    td[j] = __expf(-__expf(tdec[h0 + j]));
    etf[j] = __expf(tfst[h0 + j]);
    num[j] = pnum[o + j]; den[j] = pden[o + j];
  }
  size_t idx = (size_t)b * TT * HH + (size_t)(c * LL) * HH + h0;
#pragma unroll 2
  for (int i = 0; i < LL; ++i, idx += HH) {
    const u16x8 k8 = *(const u16x8*)(k + idx);
    const u16x8 v8 = *(const u16x8*)(v + idx);
    const u16x8 r8 = *(const u16x8*)(r + idx);
    u16x8 o8;
#pragma unroll
    for (int j = 0; j < 8; ++j) {
      const float ek = __expf(bf2f(k8[j]));
      const float vt = bf2f(v8[j]);
      const float rt = bf2f(r8[j]);
      const float e = ek * etf[j];                   // exp(tf + k) = exp(k)*exp(tf)
      const float inv = __builtin_amdgcn_rcpf(den[j] + e);
      const float outv = (num[j] + e * vt) * inv;
      num[j] = td[j] * num[j] + ek * vt;
      den[j] = td[j] * den[j] + ek;
      o8[j] = f2bf(outv * rt);
    }
    *(u16x8*)(rwkv + idx) = o8;
  }
}

extern "C" void kernel_launch(void* const* d_in, const int* in_sizes, int n_in,
                              void* d_out, int out_size, void* d_ws, size_t ws_size,
                              hipStream_t stream) {
  (void)in_sizes; (void)n_in; (void)out_size; (void)ws_size;
  const float* x    = (const float*)d_in[0];
  const float* tdec = (const float*)d_in[1];
  const float* tfst = (const float*)d_in[2];
  const float* tmk  = (const float*)d_in[3];
  const float* tmv  = (const float*)d_in[4];
  const float* tmr  = (const float*)d_in[5];
  const float* Wk   = (const float*)d_in[6];
  const float* Wv   = (const float*)d_in[7];
  const float* Wr   = (const float*)d_in[8];
  const float* Wo   = (const float*)d_in[9];
  const float* bo   = (const float*)d_in[10];
  float* out = (float*)d_out;

  char* ws = (char*)d_ws;
  const size_t MiB = (size_t)1 << 20;
  unsigned short* Wbf = (unsigned short*)(ws);             //   8 MiB
  unsigned short* kin = (unsigned short*)(ws + 8 * MiB);   //  32 MiB
  unsigned short* vin = (unsigned short*)(ws + 40 * MiB);  //  32 MiB
  unsigned short* rin = (unsigned short*)(ws + 72 * MiB);  //  32 MiB
  unsigned short* rb  = (unsigned short*)(ws + 104 * MiB); //  32 MiB  (peak 136 MiB)
  // k,v bf16 staged in d_out (64 MiB fp32 buffer = 2 x 32 MiB bf16); dead before gemm_o writes.
  unsigned short* kb = (unsigned short*)out;
  unsigned short* vb = kb + (size_t)MM * HH;
  unsigned short* rwkv = kin;                  // kin dead after gemm_kvr
  float* pnum = (float*)(ws + 40 * MiB);       // vin dead after gemm_kvr (4 MiB @ CC=128)
  float* pden = (float*)(ws + 44 * MiB);       // (4 MiB)

  hipLaunchKernelGGL(conv_w, dim3(1024, 4), dim3(256), 0, stream, Wk, Wv, Wr, Wo, Wbf);
  hipLaunchKernelGGL(mix_kernel, dim3(16384), dim3(256), 0, stream,
                     x, tmk, tmv, tmr, kin, vin, rin);
  hipLaunchKernelGGL(gemm_kvr, dim3(256, 3), dim3(512), 0, stream,
                     kin, vin, rin, Wbf, kb, vb, rb);
  hipLaunchKernelGGL(wkv_part, dim3(512), dim3(256), 0, stream,
                     kb, vb, tdec, pnum, pden);
  hipLaunchKernelGGL(wkv_scan, dim3(32), dim3(256), 0, stream,
                     tdec, pnum, pden);
  hipLaunchKernelGGL(wkv_final, dim3(512), dim3(256), 0, stream,
                     kb, vb, rb, tdec, tfst, pnum, pden, rwkv);
  hipLaunchKernelGGL(gemm_o, dim3(256), dim3(512), 0, stream,
                     rwkv, Wbf + (size_t)3 * HH * HH, bo, out);
}

// Round 4
// 348.029 us; speedup vs baseline: 1.0651x; 1.0651x over previous
//
#include <hip/hip_runtime.h>
#include <hip/hip_bf16.h>
#include <cstdint>
#include <cstddef>

#define HH 1024
#define BB 8
#define TT 2048
#define MM (BB*TT)   // 16384
#define CC 128       // wkv chunks
#define LL (TT/CC)   // 16 steps per chunk

typedef __attribute__((ext_vector_type(8))) short bf16x8;
typedef __attribute__((ext_vector_type(8))) unsigned short u16x8;
typedef __attribute__((ext_vector_type(4))) float f32x4;

__device__ __forceinline__ unsigned short f2bf(float f) {
  union { float f; unsigned u; } v; v.f = f;
  return (unsigned short)((v.u + 0x7fffu + ((v.u >> 16) & 1u)) >> 16);  // RNE
}
__device__ __forceinline__ float bf2f(unsigned short s) {
  union { float f; unsigned u; } v; v.u = ((unsigned)s) << 16;
  return v.f;
}

__device__ __forceinline__ void load_lds16(const void* g, void* l) {
  __builtin_amdgcn_global_load_lds((const __attribute__((address_space(1))) void*)g,
                                   (__attribute__((address_space(3))) void*)l,
                                   16, 0, 0);
}

// ---------------- weight fp32 -> bf16 ----------------
__global__ __launch_bounds__(256) void conv_w(const float* __restrict__ Wk,
    const float* __restrict__ Wv, const float* __restrict__ Wr,
    const float* __restrict__ Wo, unsigned short* __restrict__ dst) {
  const int i = (blockIdx.x * 256 + threadIdx.x) * 4;
  const float* src = blockIdx.y == 0 ? Wk : blockIdx.y == 1 ? Wv : blockIdx.y == 2 ? Wr : Wo;
  const float4 v = *(const float4*)(src + i);
  ushort4 o; o.x = f2bf(v.x); o.y = f2bf(v.y); o.z = f2bf(v.z); o.w = f2bf(v.w);
  *(ushort4*)(dst + (size_t)blockIdx.y * HH * HH + i) = o;
}

// ---------------- time-shift + mix -> bf16 kin/vin/rin ----------------
__global__ __launch_bounds__(256) void mix_kernel(const float* __restrict__ x,
    const float* __restrict__ tmk, const float* __restrict__ tmv, const float* __restrict__ tmr,
    unsigned short* __restrict__ kin, unsigned short* __restrict__ vin,
    unsigned short* __restrict__ rin) {
  const int gid = blockIdx.x * 256 + threadIdx.x;
  const size_t e0 = (size_t)gid * 4;
  const int h = (int)(e0 & (HH - 1));
  const int t = (int)((e0 >> 10) & (TT - 1));
  const float4 xv = *(const float4*)(x + e0);
  float4 sv = make_float4(0.f, 0.f, 0.f, 0.f);
  if (t != 0) sv = *(const float4*)(x + e0 - HH);
  const float4 k4 = *(const float4*)(tmk + h);
  const float4 v4 = *(const float4*)(tmv + h);
  const float4 r4 = *(const float4*)(tmr + h);
  ushort4 ko, vo, ro;
  ko.x = f2bf(sv.x + k4.x * (xv.x - sv.x)); ko.y = f2bf(sv.y + k4.y * (xv.y - sv.y));
  ko.z = f2bf(sv.z + k4.z * (xv.z - sv.z)); ko.w = f2bf(sv.w + k4.w * (xv.w - sv.w));
  vo.x = f2bf(sv.x + v4.x * (xv.x - sv.x)); vo.y = f2bf(sv.y + v4.y * (xv.y - sv.y));
  vo.z = f2bf(sv.z + v4.z * (xv.z - sv.z)); vo.w = f2bf(sv.w + v4.w * (xv.w - sv.w));
  ro.x = f2bf(sv.x + r4.x * (xv.x - sv.x)); ro.y = f2bf(sv.y + r4.y * (xv.y - sv.y));
  ro.z = f2bf(sv.z + r4.z * (xv.z - sv.z)); ro.w = f2bf(sv.w + r4.w * (xv.w - sv.w));
  *(ushort4*)(kin + e0) = ko;
  *(ushort4*)(vin + e0) = vo;
  *(ushort4*)(rin + e0) = ro;
}

// ================= 256x256 8-phase GEMM core (r4: 3-bit block swizzle) ==========
// BM=BN=256, BK=64, 8 waves (2M x 4N), LDS 128 KiB (2 dbuf x A/B x 256x64 bf16).
// Bank analysis (r2/r3 post-mortem): a ds_read_b128 lane occupies one 4-bank QUAD
// (byte bits 4-6). r2/r3 swizzles left 4 lanes of every aligned-8 beat on the same
// quad -> 12 extra cy/read (measured, identical 9437184 both rounds).
// r4: LDS 16B-block b of row r holds k-block b ^ (r&7). Lane quad =
// (4*kk+kq) ^ (l15&7): any aligned 8/16/32-lane group covers quads uniformly,
// whole wave = 8 lanes/bank (minimum). Both sides same involution (rule #21):
//   read:  el-col = (kk*32+kq*8) ^ ((l15&7)<<3)
//   write: linear LDS dest; global source col = ((lane&7) ^ (lane>>3))*8
//          (row-in-8 = lane>>3; stA/stB row bases are 0 mod 8)
// vmcnt(6) only at phases 4/8 (counted vmcnt); final vmcnt(0) drain before exit.

#define BAR()   do { asm volatile("" ::: "memory"); __builtin_amdgcn_s_barrier(); \
                     asm volatile("" ::: "memory"); } while (0)
#define LGKM0() asm volatile("s_waitcnt lgkmcnt(0)" ::: "memory")
#define VM6()   asm volatile("s_waitcnt vmcnt(6)" ::: "memory")
#define VM0()   asm volatile("s_waitcnt vmcnt(0)" ::: "memory")

__device__ __forceinline__ void stA(const unsigned short* __restrict__ Ag, int m0, int kt,
                                    unsigned short* buf, int h, int w, int rl, int scol) {
#pragma unroll
  for (int l = 0; l < 2; ++l) {
    const int row = l * 128 + h * 64 + w * 8;          // wave-uniform dest row base (0 mod 8)
    load_lds16(Ag + (size_t)(m0 + row + rl) * HH + kt + scol, buf + row * 64);
  }
}
__device__ __forceinline__ void stB(const unsigned short* __restrict__ Bg, int n0, int kt,
                                    unsigned short* buf, int h, int w, int rl, int scol) {
#pragma unroll
  for (int l = 0; l < 2; ++l) {
    const int row = (2 * (l * 2 + (w >> 2)) + h) * 32 + (w & 3) * 8;   // 0 mod 8
    load_lds16(Bg + (size_t)(n0 + row + rl) * HH + kt + scol, buf + row * 64);
  }
}

template<int MH>
__device__ __forceinline__ void rdA(const unsigned short* buf, bf16x8 (&af)[4][2],
                                    int wm, int l15, int kq, int swz) {
#pragma unroll
  for (int fm = 0; fm < 4; ++fm)
#pragma unroll
    for (int kk = 0; kk < 2; ++kk)
      af[fm][kk] = *(const bf16x8*)(buf + (wm * 128 + MH * 64 + fm * 16 + l15) * 64
                                        + ((kk * 32 + kq * 8) ^ swz));
}
template<int NH>
__device__ __forceinline__ void rdB(const unsigned short* buf, bf16x8 (&bfr)[2][2][2],
                                    int wn, int l15, int kq, int swz) {
#pragma unroll
  for (int fn = 0; fn < 2; ++fn)
#pragma unroll
    for (int kk = 0; kk < 2; ++kk)
      bfr[NH][fn][kk] = *(const bf16x8*)(buf + (wn * 64 + NH * 32 + fn * 16 + l15) * 64
                                             + ((kk * 32 + kq * 8) ^ swz));
}
template<int MH, int NH>
__device__ __forceinline__ void mfmaQ(f32x4 (&acc)[8][4], const bf16x8 (&af)[4][2],
                                      const bf16x8 (&bfr)[2][2][2]) {
  __builtin_amdgcn_s_setprio(1);
#pragma unroll
  for (int kk = 0; kk < 2; ++kk)
#pragma unroll
    for (int fm = 0; fm < 4; ++fm)
#pragma unroll
      for (int fn = 0; fn < 2; ++fn)
        acc[MH * 4 + fm][NH * 2 + fn] = __builtin_amdgcn_mfma_f32_16x16x32_bf16(
            af[fm][kk], bfr[NH][fn][kk], acc[MH * 4 + fm][NH * 2 + fn], 0, 0, 0);
  __builtin_amdgcn_s_setprio(0);
}

__device__ __forceinline__ void gemm256(const unsigned short* __restrict__ Ag,
                                        const unsigned short* __restrict__ Bg,
                                        const int m0, const int n0,
                                        unsigned short* As, unsigned short* Bs,
                                        f32x4 (&acc)[8][4]) {
  const int tid = threadIdx.x;
  const int lane = tid & 63;
  const int w = tid >> 6;
  const int wm = w >> 2, wn = w & 3;
  const int l15 = lane & 15, kq = lane >> 4;
  // read-side XOR: k-block index ^= row&7 (row&7 == l15&7 for all fragment rows)
  const int swz = (l15 & 7) << 3;
  const int rl = lane >> 3;                                     // stage dest row-in-8
  // write-side: linear dest; source k-block = (lane&7) ^ row-in-8
  const int scol = ((lane & 7) ^ rl) * 8;
  unsigned short* const A0 = As;
  unsigned short* const A1 = As + 256 * 64;
  unsigned short* const B0 = Bs;
  unsigned short* const B1 = Bs + 256 * 64;
  bf16x8 af[4][2], bfr[2][2][2];

  // prologue: tile0 -> buf0 (8 loads), tile1 A0,B0,B1 -> buf1 (6 loads); drain buf0.
  stA(Ag, m0, 0, A0, 0, w, rl, scol);
  stB(Bg, n0, 0, B0, 0, w, rl, scol);
  stB(Bg, n0, 0, B0, 1, w, rl, scol);
  stA(Ag, m0, 0, A0, 1, w, rl, scol);
  stA(Ag, m0, 64, A1, 0, w, rl, scol);
  stB(Bg, n0, 64, B1, 0, w, rl, scol);
  stB(Bg, n0, 64, B1, 1, w, rl, scol);
  VM6(); BAR();

#pragma unroll 1
  for (int i = 0; i < 8; ++i) {
    const int tb1 = ((2 * i + 1) * 64) & (HH - 1);  // buf1 current tile (A1 staged ph1)
    const int tn0 = ((2 * i + 2) * 64) & (HH - 1);  // buf0 next tile (wraps harmlessly @end)
    const int tn1 = ((2 * i + 3) * 64) & (HH - 1);  // buf1 next tile
    // ph1: compute (mh0,nh0) of buf0; stage buf1.A-h1 (WAR: read ph7 prev iter)
    rdA<0>(A0, af, wm, l15, kq, swz); rdB<0>(B0, bfr, wn, l15, kq, swz);
    stA(Ag, m0, tb1, A1, 1, w, rl, scol);
    BAR(); LGKM0(); mfmaQ<0, 0>(acc, af, bfr); BAR();
    // ph2: (mh0,nh1); stage buf0.A-h0 (read ph1)
    rdB<1>(B0, bfr, wn, l15, kq, swz);
    stA(Ag, m0, tn0, A0, 0, w, rl, scol);
    BAR(); LGKM0(); mfmaQ<0, 1>(acc, af, bfr); BAR();
    // ph3: (mh1,nh1); stage buf0.B-h0 (read ph1)
    rdA<1>(A0, af, wm, l15, kq, swz);
    stB(Bg, n0, tn0, B0, 0, w, rl, scol);
    BAR(); LGKM0(); mfmaQ<1, 1>(acc, af, bfr); BAR();
    // ph4: (mh1,nh0); stage buf0.B-h1 (read ph2); counted vmcnt (drains buf1 cur tile)
    stB(Bg, n0, tn0, B0, 1, w, rl, scol);
    VM6(); BAR(); LGKM0(); mfmaQ<1, 0>(acc, af, bfr); BAR();
    // ph5: (mh0,nh0) of buf1; stage buf0.A-h1 (read ph3)
    rdA<0>(A1, af, wm, l15, kq, swz); rdB<0>(B1, bfr, wn, l15, kq, swz);
    stA(Ag, m0, tn0, A0, 1, w, rl, scol);
    BAR(); LGKM0(); mfmaQ<0, 0>(acc, af, bfr); BAR();
    // ph6: (mh0,nh1); stage buf1.A-h0 (read ph5)
    rdB<1>(B1, bfr, wn, l15, kq, swz);
    stA(Ag, m0, tn1, A1, 0, w, rl, scol);
    BAR(); LGKM0(); mfmaQ<0, 1>(acc, af, bfr); BAR();
    // ph7: (mh1,nh1); stage buf1.B-h0 (read ph5)
    rdA<1>(A1, af, wm, l15, kq, swz);
    stB(Bg, n0, tn1, B1, 0, w, rl, scol);
    BAR(); LGKM0(); mfmaQ<1, 1>(acc, af, bfr); BAR();
    // ph8: (mh1,nh0); stage buf1.B-h1 (read ph6); counted vmcnt (drains buf0 next tile)
    stB(Bg, n0, tn1, B1, 1, w, rl, scol);
    VM6(); BAR(); LGKM0(); mfmaQ<1, 0>(acc, af, bfr); BAR();
  }
  // no DMA may outlive this workgroup's LDS allocation (1 wg/CU -> successor reuses it)
  VM0();
}

// XCD-aware swizzle for 256 wgs (0 mod 8 -> bijective): 32 contiguous tiles per XCD.
__device__ __forceinline__ void swizzle_mn256(int x, int& m0, int& n0) {
  const int wg = (x & 7) * 32 + (x >> 3);
  m0 = (wg >> 2) * 256;          // 64 m-tiles
  n0 = (wg & 3) * 256;           // 4 n-tiles
}

// z=0: k -> bf16, z=1: v -> bf16, z=2: r -> sigmoid -> bf16
__global__ __launch_bounds__(512, 2) void gemm_kvr(const unsigned short* __restrict__ kin,
    const unsigned short* __restrict__ vin, const unsigned short* __restrict__ rin,
    const unsigned short* __restrict__ Wbf,
    unsigned short* __restrict__ kb, unsigned short* __restrict__ vb,
    unsigned short* __restrict__ rb) {
  __shared__ unsigned short As[2 * 256 * 64];
  __shared__ unsigned short Bs[2 * 256 * 64];
  const int z = blockIdx.y;
  const unsigned short* Ag = z == 0 ? kin : (z == 1 ? vin : rin);
  const unsigned short* Bg = Wbf + (size_t)z * HH * HH;
  unsigned short* Cg = z == 0 ? kb : (z == 1 ? vb : rb);
  int m0, n0; swizzle_mn256(blockIdx.x, m0, n0);
  f32x4 acc[8][4] = {};
  gemm256(Ag, Bg, m0, n0, As, Bs, acc);
  const int lane = threadIdx.x & 63, w = threadIdx.x >> 6;
  const int wm = w >> 2, wn = w & 3, l15 = lane & 15, lq = lane >> 4;
  const bool sig = (z == 2);
#pragma unroll
  for (int fm = 0; fm < 8; ++fm)
#pragma unroll
    for (int fn = 0; fn < 4; ++fn) {
      const int col = n0 + wn * 64 + fn * 16 + l15;
      const int r0 = m0 + wm * 128 + fm * 16 + lq * 4;
#pragma unroll
      for (int j = 0; j < 4; ++j) {
        float vv = acc[fm][fn][j];
        if (sig) vv = 1.0f / (1.0f + __expf(-vv));
        Cg[(size_t)(r0 + j) * HH + col] = f2bf(vv);
      }
    }
}

// out = rwkv @ Wo^T + bo  (fp32 out)
__global__ __launch_bounds__(512, 2) void gemm_o(const unsigned short* __restrict__ Ag,
    const unsigned short* __restrict__ Bg, const float* __restrict__ bias,
    float* __restrict__ C) {
  __shared__ unsigned short As[2 * 256 * 64];
  __shared__ unsigned short Bs[2 * 256 * 64];
  int m0, n0; swizzle_mn256(blockIdx.x, m0, n0);
  f32x4 acc[8][4] = {};
  gemm256(Ag, Bg, m0, n0, As, Bs, acc);
  const int lane = threadIdx.x & 63, w = threadIdx.x >> 6;
  const int wm = w >> 2, wn = w & 3, l15 = lane & 15, lq = lane >> 4;
#pragma unroll
  for (int fm = 0; fm < 8; ++fm)
#pragma unroll
    for (int fn = 0; fn < 4; ++fn) {
      const int col = n0 + wn * 64 + fn * 16 + l15;
      const float bv = bias[col];
      const int r0 = m0 + wm * 128 + fm * 16 + lq * 4;
#pragma unroll
      for (int j = 0; j < 4; ++j)
        C[(size_t)(r0 + j) * HH + col] = acc[fm][fn][j] + bv;
    }
}

// ---------------- WKV: chunk-parallel scan over T (8-wide vectorized) ----------------
__global__ __launch_bounds__(256) void wkv_part(const unsigned short* __restrict__ k,
    const unsigned short* __restrict__ v, const float* __restrict__ tdec,
    float* __restrict__ pnum, float* __restrict__ pden) {
  const int gid = blockIdx.x * 256 + threadIdx.x;   // 0 .. CC*BB*HH/8-1
  const int h0 = (gid & 127) * 8;
  const int b = (gid >> 7) & (BB - 1);
  const int c = gid >> 10;
  float td[8], num[8], den[8];
#pragma unroll
  for (int j = 0; j < 8; ++j) {
    td[j] = __expf(-__expf(tdec[h0 + j]));
    num[j] = 0.f; den[j] = 0.f;
  }
  size_t idx = (size_t)b * TT * HH + (size_t)(c * LL) * HH + h0;
#pragma unroll 4
  for (int i = 0; i < LL; ++i, idx += HH) {
    const u16x8 k8 = *(const u16x8*)(k + idx);
    const u16x8 v8 = *(const u16x8*)(v + idx);
#pragma unroll
    for (int j = 0; j < 8; ++j) {
      const float ek = __expf(bf2f(k8[j]));
      num[j] = td[j] * num[j] + ek * bf2f(v8[j]);
      den[j] = td[j] * den[j] + ek;
    }
  }
  const size_t o = (size_t)c * (BB * HH) + b * HH + h0;
#pragma unroll
  for (int j = 0; j < 8; ++j) { pnum[o + j] = num[j]; pden[o + j] = den[j]; }
}

__global__ __launch_bounds__(256) void wkv_scan(const float* __restrict__ tdec,
    float* __restrict__ pnum, float* __restrict__ pden) {
  const int bh = blockIdx.x * 256 + threadIdx.x;     // 0..8191
  const int h = bh & (HH - 1);
  const float ed = __expf(tdec[h]);
  const float tdL = __expf(-ed * (float)LL);         // td^LL exactly
  float num = 0.f, den = 0.f;
#pragma unroll 8
  for (int c = 0; c < CC; ++c) {
    const size_t o = (size_t)c * (BB * HH) + bh;
    const float tn = pnum[o], td_ = pden[o];
    pnum[o] = num; pden[o] = den;
    num = tdL * num + tn;
    den = tdL * den + td_;
  }
}

__global__ __launch_bounds__(256) void wkv_final(const unsigned short* __restrict__ k,
    const unsigned short* __restrict__ v, const unsigned short* __restrict__ r,
    const float* __restrict__ tdec, const float* __restrict__ tfst,
    const float* __restrict__ pnum, const float* __restrict__ pden,
    unsigned short* __restrict__ rwkv) {
  const int gid = blockIdx.x * 256 + threadIdx.x;   // 0 .. CC*BB*HH/8-1
  const int h0 = (gid & 127) * 8;
  const int b = (gid >> 7) & (BB - 1);
  const int c = gid >> 10;
  float td[8], etf[8], num[8], den[8];
  const size_t o = (size_t)c * (BB * HH) + b * HH + h0;
#pragma unroll
  for (int j = 0; j < 8; ++j) {
    td[j] = __expf(-__expf(tdec[h0 + j]));
    etf[j] = __expf(tfst[h0 + j]);
    num[j] = pnum[o + j]; den[j] = pden[o + j];
  }
  size_t idx = (size_t)b * TT * HH + (size_t)(c * LL) * HH + h0;
#pragma unroll 2
  for (int i = 0; i < LL; ++i, idx += HH) {
    const u16x8 k8 = *(const u16x8*)(k + idx);
    const u16x8 v8 = *(const u16x8*)(v + idx);
    const u16x8 r8 = *(const u16x8*)(r + idx);
    u16x8 o8;
#pragma unroll
    for (int j = 0; j < 8; ++j) {
      const float ek = __expf(bf2f(k8[j]));
      const float vt = bf2f(v8[j]);
      const float rt = bf2f(r8[j]);
      const float e = ek * etf[j];                   // exp(tf + k) = exp(k)*exp(tf)
      const float inv = __builtin_amdgcn_rcpf(den[j] + e);
      const float outv = (num[j] + e * vt) * inv;
      num[j] = td[j] * num[j] + ek * vt;
      den[j] = td[j] * den[j] + ek;
      o8[j] = f2bf(outv * rt);
    }
    *(u16x8*)(rwkv + idx) = o8;
  }
}

extern "C" void kernel_launch(void* const* d_in, const int* in_sizes, int n_in,
                              void* d_out, int out_size, void* d_ws, size_t ws_size,
                              hipStream_t stream) {
  (void)in_sizes; (void)n_in; (void)out_size; (void)ws_size;
  const float* x    = (const float*)d_in[0];
  const float* tdec = (const float*)d_in[1];
  const float* tfst = (const float*)d_in[2];
  const float* tmk  = (const float*)d_in[3];
  const float* tmv  = (const float*)d_in[4];
  const float* tmr  = (const float*)d_in[5];
  const float* Wk   = (const float*)d_in[6];
  const float* Wv   = (const float*)d_in[7];
  const float* Wr   = (const float*)d_in[8];
  const float* Wo   = (const float*)d_in[9];
  const float* bo   = (const float*)d_in[10];
  float* out = (float*)d_out;

  char* ws = (char*)d_ws;
  const size_t MiB = (size_t)1 << 20;
  unsigned short* Wbf = (unsigned short*)(ws);             //   8 MiB
  unsigned short* kin = (unsigned short*)(ws + 8 * MiB);   //  32 MiB
  unsigned short* vin = (unsigned short*)(ws + 40 * MiB);  //  32 MiB
  unsigned short* rin = (unsigned short*)(ws + 72 * MiB);  //  32 MiB
  unsigned short* rb  = (unsigned short*)(ws + 104 * MiB); //  32 MiB  (peak 136 MiB)
  // k,v bf16 staged in d_out (64 MiB fp32 buffer = 2 x 32 MiB bf16); dead before gemm_o writes.
  unsigned short* kb = (unsigned short*)out;
  unsigned short* vb = kb + (size_t)MM * HH;
  unsigned short* rwkv = kin;                  // kin dead after gemm_kvr
  float* pnum = (float*)(ws + 40 * MiB);       // vin dead after gemm_kvr (4 MiB @ CC=128)
  float* pden = (float*)(ws + 44 * MiB);       // (4 MiB)

  hipLaunchKernelGGL(conv_w, dim3(1024, 4), dim3(256), 0, stream, Wk, Wv, Wr, Wo, Wbf);
  hipLaunchKernelGGL(mix_kernel, dim3(16384), dim3(256), 0, stream,
                     x, tmk, tmv, tmr, kin, vin, rin);
  hipLaunchKernelGGL(gemm_kvr, dim3(256, 3), dim3(512), 0, stream,
                     kin, vin, rin, Wbf, kb, vb, rb);
  hipLaunchKernelGGL(wkv_part, dim3(512), dim3(256), 0, stream,
                     kb, vb, tdec, pnum, pden);
  hipLaunchKernelGGL(wkv_scan, dim3(32), dim3(256), 0, stream,
                     tdec, pnum, pden);
  hipLaunchKernelGGL(wkv_final, dim3(512), dim3(256), 0, stream,
                     kb, vb, rb, tdec, tfst, pnum, pden, rwkv);
  hipLaunchKernelGGL(gemm_o, dim3(256), dim3(512), 0, stream,
                     rwkv, Wbf + (size_t)3 * HH * HH, bo, out);
}